// Round 2
// baseline (520.044 us; speedup 1.0000x reference)
//
#include <hip/hip_runtime.h>
#include <math.h>

// ---------------------------------------------------------------------------
// IPOT on MI355X — round 7.
// Math (exact, verified in R1-R6):
//   Cl = -C;  M_t = exp((t+1)*Cl)
//   row:  r_i = sum_j M_t(i,j) s_j ; a = 1/(n r)
//   col:  c_j = sum_i M_t(i,j) a_i ; b = 1/c (2^10 inj); s' = b^2/b_prev/1024
//   final G(A,B) = (1/(256*1024)) sum_k P(k,A) R(k,B)
// R7 (R6 null result proved critical path = cross-WG sync chain, not compute):
//   - 2-hop sync: per-WG slots cvec[3][32][1024], plain relaxed agent stores,
//     SIGN-PARITY TAGGED (even iter -> -v, odd -> +v; all partials > 0).
//     3-buffer rotation + odd period => successive occupants of an address
//     alternate tag => readers poll data directly (no counters, no atomics,
//     no zeroing, no tid0 broadcast). Reader accepts slot iff tag matches.
//   - a broadcast in-register (xor-reduce leaves sum in all lanes): aL gone,
//     2 syncthreads/iter instead of 3.
//   - stride-66 padded LDS for sL/buf: scalar conflict-free ds ops replace
//     16-way-conflicted float4s (R6: 3.7M conflict cycles).
// ---------------------------------------------------------------------------

#define NWG 32
#define TPB 1024
#define NIT 50

typedef unsigned long long ull;

// ws offsets in floats
constexpr int CL_OFF   = 0;              // -C [1024*1024]
constexpr int CVEC_OFF = 1024 * 1024;    // [3][NWG][1024] tagged col partials
// total ~ 4.37 MB

// ---------------- C = 1 - xhat yhat^T (norms fused) ; Cl = -C ---------------
__global__ __launch_bounds__(256) void k_gemm(const float* __restrict__ X,
                                              const float* __restrict__ Y,
                                              float* __restrict__ ws) {
    __shared__ float As[32][68];
    __shared__ float Bs[32][68];
    __shared__ float nX[64], nY[64];
    float* Cl = ws + CL_OFF;

    int tid = threadIdx.x;
    int tx = tid & 15, ty = tid >> 4;
    int bx = blockIdx.x, by = blockIdx.y;
    int lr0 = tid >> 3;          // 0..31
    int kq  = (tid & 7) * 4;     // 0..28

    float acc[4][4] = {};
    float sx0 = 0.f, sx1 = 0.f, sy0 = 0.f, sy1 = 0.f;
    for (int k0 = 0; k0 < 512; k0 += 32) {
        float4 xa = *(const float4*)(X + (size_t)(by * 64 + lr0) * 512 + k0 + kq);
        float4 xb = *(const float4*)(X + (size_t)(by * 64 + lr0 + 32) * 512 + k0 + kq);
        float4 ya = *(const float4*)(Y + (size_t)(bx * 64 + lr0) * 512 + k0 + kq);
        float4 yb = *(const float4*)(Y + (size_t)(bx * 64 + lr0 + 32) * 512 + k0 + kq);
        sx0 += xa.x * xa.x + xa.y * xa.y + xa.z * xa.z + xa.w * xa.w;
        sx1 += xb.x * xb.x + xb.y * xb.y + xb.z * xb.z + xb.w * xb.w;
        sy0 += ya.x * ya.x + ya.y * ya.y + ya.z * ya.z + ya.w * ya.w;
        sy1 += yb.x * yb.x + yb.y * yb.y + yb.z * yb.z + yb.w * yb.w;
        As[kq + 0][lr0] = xa.x; As[kq + 1][lr0] = xa.y;
        As[kq + 2][lr0] = xa.z; As[kq + 3][lr0] = xa.w;
        As[kq + 0][lr0 + 32] = xb.x; As[kq + 1][lr0 + 32] = xb.y;
        As[kq + 2][lr0 + 32] = xb.z; As[kq + 3][lr0 + 32] = xb.w;
        Bs[kq + 0][lr0] = ya.x; Bs[kq + 1][lr0] = ya.y;
        Bs[kq + 2][lr0] = ya.z; Bs[kq + 3][lr0] = ya.w;
        Bs[kq + 0][lr0 + 32] = yb.x; Bs[kq + 1][lr0 + 32] = yb.y;
        Bs[kq + 2][lr0 + 32] = yb.z; Bs[kq + 3][lr0 + 32] = yb.w;
        __syncthreads();
#pragma unroll
        for (int kk = 0; kk < 32; ++kk) {
            float4 a4 = *(const float4*)&As[kk][4 * ty];
            float4 b4 = *(const float4*)&Bs[kk][4 * tx];
            float av[4] = {a4.x, a4.y, a4.z, a4.w};
            float bv[4] = {b4.x, b4.y, b4.z, b4.w};
#pragma unroll
            for (int r = 0; r < 4; ++r)
#pragma unroll
                for (int q = 0; q < 4; ++q) acc[r][q] += av[r] * bv[q];
        }
        __syncthreads();
    }
#pragma unroll
    for (int m = 1; m < 8; m <<= 1) {
        sx0 += __shfl_xor(sx0, m, 64);
        sx1 += __shfl_xor(sx1, m, 64);
        sy0 += __shfl_xor(sy0, m, 64);
        sy1 += __shfl_xor(sy1, m, 64);
    }
    if ((tid & 7) == 0) {
        nX[lr0] = sx0; nX[lr0 + 32] = sx1;
        nY[lr0] = sy0; nY[lr0 + 32] = sy1;
    }
    __syncthreads();

    int i0 = by * 64 + 4 * ty, j0 = bx * 64 + 4 * tx;
    float vy[4];
#pragma unroll
    for (int q = 0; q < 4; ++q) vy[q] = 1.0f / sqrtf(nY[4 * tx + q]);
#pragma unroll
    for (int r = 0; r < 4; ++r) {
        float vx = 1.0f / sqrtf(nX[4 * ty + r]);
        float4 o;
        o.x = acc[r][0] * vx * vy[0] - 1.0f;  // Cl = dot - 1 = -C
        o.y = acc[r][1] * vx * vy[1] - 1.0f;
        o.z = acc[r][2] * vx * vy[2] - 1.0f;
        o.w = acc[r][3] * vx * vy[3] - 1.0f;
        *(float4*)(Cl + (size_t)(i0 + r) * 1024 + j0) = o;
    }
}

// ---------------------- persistent IPOT iteration --------------------------
__global__ __launch_bounds__(1024, 4) void k_ipot(float* __restrict__ ws,
                                                  float* __restrict__ out) {
    __shared__ float sLp[1056];        // s (loop) / b (epilogue): [u][l], stride 66
    __shared__ float buf[16 * 1056];   // col partials [wave][u*66+lane]; epi Ps/Rs
    __shared__ float twv[16];

    const int g = blockIdx.x, tid = threadIdx.x;
    const int rs = tid >> 6, lane = tid & 63;   // wave id (0..15) / lane
    const int uo = tid & 15, lo = tid >> 4;     // owned col tid = lo*16+uo
    float* Cl   = ws + CL_OFF;
    float* cvec = ws + CVEC_OFF;

    // thread owns rows g*32 + rs*2 + i (i<2), cols lane*16 + u (u<16)
    float C[2][16], E[2][16];
#pragma unroll
    for (int i = 0; i < 2; ++i) {
        const float* src = Cl + (size_t)(g * 32 + rs * 2 + i) * 1024 + lane * 16;
#pragma unroll
        for (int q = 0; q < 4; ++q) {
            float4 c = *(const float4*)(src + 4 * q);
            C[i][4 * q + 0] = c.x; C[i][4 * q + 1] = c.y;
            C[i][4 * q + 2] = c.z; C[i][4 * q + 3] = c.w;
        }
    }
#pragma unroll
    for (int i = 0; i < 2; ++i)
#pragma unroll
        for (int u = 0; u < 16; ++u) E[i][u] = __expf(C[i][u]);  // round 0

    float bv = 1.0f;            // b_prev for owned col (= tid)
    float a0 = 0.0f, a1 = 0.0f; // this wave's row scalings (all lanes)

    for (int t = 0; t < NIT; ++t) {
        float sval;
        if (t == 0) {
            sval = 1.0f / 1024.0f;
        } else {
            // data-poll readback of iter t-1 partials (32 slots, tag-checked)
            const float* rb = cvec + ((t - 1) % 3) * (NWG * 1024) + tid;
            const bool expneg = ((t - 1) & 1) == 0;  // even iter stored -v
            float ssum = 0.0f;
            long gd = 0;
            for (;;) {
                ssum = 0.0f;
                unsigned bad = 0u;
#pragma unroll
                for (int s2 = 0; s2 < NWG; ++s2) {
                    float v = __hip_atomic_load(rb + s2 * 1024, __ATOMIC_RELAXED,
                                                __HIP_MEMORY_SCOPE_AGENT);
                    unsigned bits = __float_as_uint(v);
                    bad |= expneg ? (unsigned)(bits <= 0x80000000u)
                                  : (unsigned)(bits == 0u || bits >= 0x80000000u);
                    ssum += v;
                }
                if (!bad) break;
                if (++gd > 100000) break;  // anti-hang bailout
                __builtin_amdgcn_s_sleep(1);
            }
            float c = expneg ? -ssum : ssum;
            float b = 1.0f / c;
            sval = b * b / bv * (1.0f / 1024.0f);  // 2^-10 inj
            bv = b;
        }
        sLp[uo * 66 + lo] = sval;   // s for col tid at [tid&15][tid>>4]
        __syncthreads();

        // row phase: rp[i] = sum_u E[i][u] * s[lane*16+u]; xor-reduce -> all lanes
        float sv[16];
#pragma unroll
        for (int u = 0; u < 16; ++u) sv[u] = sLp[u * 66 + lane];
        float rp0 = 0.0f, rp1 = 0.0f;
#pragma unroll
        for (int u = 0; u < 16; ++u) {
            rp0 += E[0][u] * sv[u];
            rp1 += E[1][u] * sv[u];
        }
#pragma unroll
        for (int m = 1; m < 64; m <<= 1) {
            rp0 += __shfl_xor(rp0, m, 64);
            rp1 += __shfl_xor(rp1, m, 64);
        }
        a0 = 1.0f / (1024.0f * rp0);
        a1 = 1.0f / (1024.0f * rp1);

        // col phase: this wave's 2-row partials for its 16 cols (padded layout)
#pragma unroll
        for (int u = 0; u < 16; ++u)
            buf[rs * 1056 + u * 66 + lane] = E[0][u] * a0 + E[1][u] * a1;
        __syncthreads();

        // owner (col tid): sum 16 wave-partials, tagged store to slot g
        float csum = 0.0f;
#pragma unroll
        for (int w = 0; w < 16; ++w) csum += buf[w * 1056 + uo * 66 + lo];
        float tagged = (t & 1) ? csum : -csum;  // odd -> +, even -> -
        __hip_atomic_store(cvec + (t % 3) * (NWG * 1024) + g * 1024 + tid, tagged,
                           __ATOMIC_RELAXED, __HIP_MEMORY_SCOPE_AGENT);

        // recompute E for next round (overlaps store->load sync latency)
        if (t < NIT - 1) {
            const float kf = (float)(t + 2);
#pragma unroll
            for (int i = 0; i < 2; ++i)
#pragma unroll
                for (int u = 0; u < 16; ++u) E[i][u] = __expf(kf * C[i][u]);
        }
    }

    // ------------- epilogue: E = exp(50*Cl), a0/a1 = round-49 a -------------
    {   // final b for owned col: poll iter-49 partials (odd -> positive tags)
        const float* rb = cvec + ((NIT - 1) % 3) * (NWG * 1024) + tid;
        float ssum = 0.0f;
        long gd = 0;
        for (;;) {
            ssum = 0.0f;
            unsigned bad = 0u;
#pragma unroll
            for (int s2 = 0; s2 < NWG; ++s2) {
                float v = __hip_atomic_load(rb + s2 * 1024, __ATOMIC_RELAXED,
                                            __HIP_MEMORY_SCOPE_AGENT);
                unsigned bits = __float_as_uint(v);
                bad |= (unsigned)(bits == 0u || bits >= 0x80000000u);
                ssum += v;
            }
            if (!bad) break;
            if (++gd > 100000) break;
            __builtin_amdgcn_s_sleep(1);
        }
        sLp[uo * 66 + lo] = 1.0f / ssum;   // b for col tid
    }
    __syncthreads();

    // P(k,A=lane) and R(k,B=lane) for this thread's 2 rows (A-block == lane)
    float* Ps = buf;          // [32][64]
    float* Rs = buf + 2048;   // [32][64]
    float bl[16];
#pragma unroll
    for (int u = 0; u < 16; ++u) bl[u] = sLp[u * 66 + lane];
    {
        float p0 = 0.0f, r0 = 0.0f, p1 = 0.0f, r1 = 0.0f;
#pragma unroll
        for (int u = 0; u < 16; ++u) {
            p0 += C[0][u]; r0 += E[0][u] * bl[u];
            p1 += C[1][u]; r1 += E[1][u] * bl[u];
        }
        Ps[(rs * 2 + 0) * 64 + lane] = -p0;            // C = -Cl
        Rs[(rs * 2 + 0) * 64 + lane] = a0 * r0;
        Ps[(rs * 2 + 1) * 64 + lane] = -p1;
        Rs[(rs * 2 + 1) * 64 + lane] = a1 * r1;
    }
    __syncthreads();

    // G partial (this WG's 32 k-rows) -> atomicAdd into zeroed d_out
    float Rk[32];
#pragma unroll
    for (int k = 0; k < 32; ++k) Rk[k] = Rs[k * 64 + lane];  // B = lane
    const float sc = 1.0f / (256.0f * 1024.0f);
    float tsum = 0.0f;
#pragma unroll
    for (int q = 0; q < 4; ++q) {
        int o = tid + 1024 * q;
        int A = o >> 6;  // = rs + 16*q
        float acc = 0.0f;
#pragma unroll
        for (int k = 0; k < 32; ++k) acc += Ps[k * 64 + A] * Rk[k];
        float val = acc * sc;
        atomicAdd(out + o, val);
        if (A == lane) tsum += val;
    }
#pragma unroll
    for (int m = 1; m < 64; m <<= 1) tsum += __shfl_xor(tsum, m, 64);
    if (lane == 0) twv[rs] = tsum;
    __syncthreads();
    if (tid == 0) {
        float ts = 0.0f;
#pragma unroll
        for (int w = 0; w < 16; ++w) ts += twv[w];
        atomicAdd(out + 4096, ts);
    }
}

// ---------------------------------------------------------------------------
extern "C" void kernel_launch(void* const* d_in, const int* in_sizes, int n_in,
                              void* d_out, int out_size, void* d_ws, size_t ws_size,
                              hipStream_t stream) {
    const float* X = (const float*)d_in[0];  // t_prob [1024,512]
    const float* Y = (const float*)d_in[1];  // v_prob [1024,512]
    float* out = (float*)d_out;              // [64*64 + 1]
    float* ws  = (float*)d_ws;

    // zero cvec (ws poisoned each call; tags rely on clean zeros), zero d_out
    (void)hipMemsetAsync((char*)d_ws + (size_t)CVEC_OFF * 4, 0,
                         (size_t)(3 * NWG * 1024) * 4, stream);
    (void)hipMemsetAsync(d_out, 0, (size_t)out_size * 4, stream);

    k_gemm<<<dim3(16, 16), 256, 0, stream>>>(X, Y, ws);
    k_ipot<<<NWG, TPB, 0, stream>>>(ws, out);
}

// Round 3
// 434.431 us; speedup vs baseline: 1.1971x; 1.1971x over previous
//
#include <hip/hip_runtime.h>
#include <math.h>

// ---------------------------------------------------------------------------
// IPOT on MI355X — round 8.
// Math (exact, verified in R1-R7):
//   Cl = -C;  M_t = exp((t+1)*Cl)
//   row:  r_i = sum_j M_t(i,j) s_j ; a = 1/(n r)
//   col:  c_j = sum_i M_t(i,j) a_i ; b = 1/c (2^10 inj); s' = b^2/b_prev/1024
//   final G(A,B) = (1/(256*1024)) sum_k P(k,A) R(k,B)
// R8 (R7 regression isolated to per-thread 32-load poll-retry batches):
//   - Flag/data split: producers do plain relaxed agent stores of col
//     partials (no atomics, no chain), __syncthreads (vmcnt drain => data
//     ack'd at LLC), then tid0 stores ONE sign-parity-tagged flag
//     (even iter -> -1, odd -> +1; 3-buffer rotation, memset-0 init).
//   - Wave 0 ALONE polls the 32 flags (1 load/lane/round); other waves park
//     at the barrier (R6's cheap-poll economy). Readback is then a one-shot
//     guaranteed-ready 32-load sum per thread (1 LLC RT, no retries),
//     same slot order as R7 (bit-identical association).
//   - No zeroing pass at all; only the 12 KB flag region is memset.
//   - R7's conflict-free padded LDS + in-register a-broadcast kept.
// ---------------------------------------------------------------------------

#define NWG 32
#define TPB 1024
#define NIT 50

typedef unsigned long long ull;

// ws offsets in floats
constexpr int CL_OFF   = 0;                          // -C [1024*1024]
constexpr int CVEC_OFF = 1024 * 1024;                // [3][NWG][1024] col partials
constexpr int FLG_OFF  = CVEC_OFF + 3 * NWG * 1024;  // [3][NWG][32] tagged flags
// total ~ 4.6 MB

// ---------------- C = 1 - xhat yhat^T (norms fused) ; Cl = -C ---------------
__global__ __launch_bounds__(256) void k_gemm(const float* __restrict__ X,
                                              const float* __restrict__ Y,
                                              float* __restrict__ ws) {
    __shared__ float As[32][68];
    __shared__ float Bs[32][68];
    __shared__ float nX[64], nY[64];
    float* Cl = ws + CL_OFF;

    int tid = threadIdx.x;
    int tx = tid & 15, ty = tid >> 4;
    int bx = blockIdx.x, by = blockIdx.y;
    int lr0 = tid >> 3;          // 0..31
    int kq  = (tid & 7) * 4;     // 0..28

    float acc[4][4] = {};
    float sx0 = 0.f, sx1 = 0.f, sy0 = 0.f, sy1 = 0.f;
    for (int k0 = 0; k0 < 512; k0 += 32) {
        float4 xa = *(const float4*)(X + (size_t)(by * 64 + lr0) * 512 + k0 + kq);
        float4 xb = *(const float4*)(X + (size_t)(by * 64 + lr0 + 32) * 512 + k0 + kq);
        float4 ya = *(const float4*)(Y + (size_t)(bx * 64 + lr0) * 512 + k0 + kq);
        float4 yb = *(const float4*)(Y + (size_t)(bx * 64 + lr0 + 32) * 512 + k0 + kq);
        sx0 += xa.x * xa.x + xa.y * xa.y + xa.z * xa.z + xa.w * xa.w;
        sx1 += xb.x * xb.x + xb.y * xb.y + xb.z * xb.z + xb.w * xb.w;
        sy0 += ya.x * ya.x + ya.y * ya.y + ya.z * ya.z + ya.w * ya.w;
        sy1 += yb.x * yb.x + yb.y * yb.y + yb.z * yb.z + yb.w * yb.w;
        As[kq + 0][lr0] = xa.x; As[kq + 1][lr0] = xa.y;
        As[kq + 2][lr0] = xa.z; As[kq + 3][lr0] = xa.w;
        As[kq + 0][lr0 + 32] = xb.x; As[kq + 1][lr0 + 32] = xb.y;
        As[kq + 2][lr0 + 32] = xb.z; As[kq + 3][lr0 + 32] = xb.w;
        Bs[kq + 0][lr0] = ya.x; Bs[kq + 1][lr0] = ya.y;
        Bs[kq + 2][lr0] = ya.z; Bs[kq + 3][lr0] = ya.w;
        Bs[kq + 0][lr0 + 32] = yb.x; Bs[kq + 1][lr0 + 32] = yb.y;
        Bs[kq + 2][lr0 + 32] = yb.z; Bs[kq + 3][lr0 + 32] = yb.w;
        __syncthreads();
#pragma unroll
        for (int kk = 0; kk < 32; ++kk) {
            float4 a4 = *(const float4*)&As[kk][4 * ty];
            float4 b4 = *(const float4*)&Bs[kk][4 * tx];
            float av[4] = {a4.x, a4.y, a4.z, a4.w};
            float bv[4] = {b4.x, b4.y, b4.z, b4.w};
#pragma unroll
            for (int r = 0; r < 4; ++r)
#pragma unroll
                for (int q = 0; q < 4; ++q) acc[r][q] += av[r] * bv[q];
        }
        __syncthreads();
    }
#pragma unroll
    for (int m = 1; m < 8; m <<= 1) {
        sx0 += __shfl_xor(sx0, m, 64);
        sx1 += __shfl_xor(sx1, m, 64);
        sy0 += __shfl_xor(sy0, m, 64);
        sy1 += __shfl_xor(sy1, m, 64);
    }
    if ((tid & 7) == 0) {
        nX[lr0] = sx0; nX[lr0 + 32] = sx1;
        nY[lr0] = sy0; nY[lr0 + 32] = sy1;
    }
    __syncthreads();

    int i0 = by * 64 + 4 * ty, j0 = bx * 64 + 4 * tx;
    float vy[4];
#pragma unroll
    for (int q = 0; q < 4; ++q) vy[q] = 1.0f / sqrtf(nY[4 * tx + q]);
#pragma unroll
    for (int r = 0; r < 4; ++r) {
        float vx = 1.0f / sqrtf(nX[4 * ty + r]);
        float4 o;
        o.x = acc[r][0] * vx * vy[0] - 1.0f;  // Cl = dot - 1 = -C
        o.y = acc[r][1] * vx * vy[1] - 1.0f;
        o.z = acc[r][2] * vx * vy[2] - 1.0f;
        o.w = acc[r][3] * vx * vy[3] - 1.0f;
        *(float4*)(Cl + (size_t)(i0 + r) * 1024 + j0) = o;
    }
}

// ---------------------- persistent IPOT iteration --------------------------
__global__ __launch_bounds__(1024, 4) void k_ipot(float* __restrict__ ws,
                                                  float* __restrict__ out) {
    __shared__ float sLp[1056];        // s (loop) / b (epilogue): [u][l], stride 66
    __shared__ float buf[16 * 1056];   // col partials [wave][u*66+lane]; epi Ps/Rs
    __shared__ float twv[16];

    const int g = blockIdx.x, tid = threadIdx.x;
    const int rs = tid >> 6, lane = tid & 63;   // wave id (0..15) / lane
    const int uo = tid & 15, lo = tid >> 4;     // owned col tid = lo*16+uo
    float* Cl   = ws + CL_OFF;
    float* cvec = ws + CVEC_OFF;
    float* flg  = ws + FLG_OFF;

    // thread owns rows g*32 + rs*2 + i (i<2), cols lane*16 + u (u<16)
    float C[2][16], E[2][16];
#pragma unroll
    for (int i = 0; i < 2; ++i) {
        const float* src = Cl + (size_t)(g * 32 + rs * 2 + i) * 1024 + lane * 16;
#pragma unroll
        for (int q = 0; q < 4; ++q) {
            float4 c = *(const float4*)(src + 4 * q);
            C[i][4 * q + 0] = c.x; C[i][4 * q + 1] = c.y;
            C[i][4 * q + 2] = c.z; C[i][4 * q + 3] = c.w;
        }
    }
#pragma unroll
    for (int i = 0; i < 2; ++i)
#pragma unroll
        for (int u = 0; u < 16; ++u) E[i][u] = __expf(C[i][u]);  // round 0

    float bv = 1.0f;            // b_prev for owned col (= tid)
    float a0 = 0.0f, a1 = 0.0f; // this wave's row scalings (all lanes)

    for (int t = 0; t < NIT; ++t) {
        float sval;
        if (t == 0) {
            sval = 1.0f / 1024.0f;
        } else {
            // wave 0 polls the 32 producer flags; other waves park at barrier
            if (rs == 0) {
                const float* fb = flg + ((t - 1) % 3) * (NWG * 32) + (lane & 31) * 32;
                const bool expneg = ((t - 1) & 1) == 0;  // even iter -> -1 flag
                long gd = 0;
                for (;;) {
                    float v = __hip_atomic_load(fb, __ATOMIC_RELAXED,
                                                __HIP_MEMORY_SCOPE_AGENT);
                    bool ok = expneg ? (v < 0.0f) : (v > 0.0f);
                    if (__all(ok)) break;
                    if (++gd > 200000) break;  // anti-hang bailout
                    __builtin_amdgcn_s_sleep(1);
                }
            }
            __syncthreads();
            // one-shot guaranteed-ready readback: 32 slots at own column
            const float* rb = cvec + ((t - 1) % 3) * (NWG * 1024) + tid;
            float c = 0.0f;
#pragma unroll
            for (int s2 = 0; s2 < NWG; ++s2)
                c += __hip_atomic_load(rb + s2 * 1024, __ATOMIC_RELAXED,
                                       __HIP_MEMORY_SCOPE_AGENT);
            float b = 1.0f / c;
            sval = b * b / bv * (1.0f / 1024.0f);  // 2^-10 inj
            bv = b;
        }
        sLp[uo * 66 + lo] = sval;   // s for col tid at [tid&15][tid>>4]
        __syncthreads();

        // row phase: rp[i] = sum_u E[i][u] * s[lane*16+u]; xor-reduce -> all lanes
        float sv[16];
#pragma unroll
        for (int u = 0; u < 16; ++u) sv[u] = sLp[u * 66 + lane];
        float rp0 = 0.0f, rp1 = 0.0f;
#pragma unroll
        for (int u = 0; u < 16; ++u) {
            rp0 += E[0][u] * sv[u];
            rp1 += E[1][u] * sv[u];
        }
#pragma unroll
        for (int m = 1; m < 64; m <<= 1) {
            rp0 += __shfl_xor(rp0, m, 64);
            rp1 += __shfl_xor(rp1, m, 64);
        }
        a0 = 1.0f / (1024.0f * rp0);
        a1 = 1.0f / (1024.0f * rp1);

        // col phase: this wave's 2-row partials for its 16 cols (padded layout)
#pragma unroll
        for (int u = 0; u < 16; ++u)
            buf[rs * 1056 + u * 66 + lane] = E[0][u] * a0 + E[1][u] * a1;
        __syncthreads();

        // owner (col tid): sum 16 wave-partials, plain store to slot g
        float csum = 0.0f;
#pragma unroll
        for (int w = 0; w < 16; ++w) csum += buf[w * 1056 + uo * 66 + lo];
        __hip_atomic_store(cvec + (t % 3) * (NWG * 1024) + g * 1024 + tid, csum,
                           __ATOMIC_RELAXED, __HIP_MEMORY_SCOPE_AGENT);
        __syncthreads();  // per-thread vmcnt drain: all 1024 stores ack'd at LLC
        if (tid == 0)
            __hip_atomic_store(flg + (t % 3) * (NWG * 32) + g * 32,
                               (t & 1) ? 1.0f : -1.0f,
                               __ATOMIC_RELAXED, __HIP_MEMORY_SCOPE_AGENT);

        // recompute E for next round (overlaps flag latency / WG skew)
        if (t < NIT - 1) {
            const float kf = (float)(t + 2);
#pragma unroll
            for (int i = 0; i < 2; ++i)
#pragma unroll
                for (int u = 0; u < 16; ++u) E[i][u] = __expf(kf * C[i][u]);
        }
    }

    // ------------- epilogue: E = exp(50*Cl), a0/a1 = round-49 a -------------
    {   // wait for iter-49 flags (odd -> +1), then one-shot readback of b
        if (rs == 0) {
            const float* fb = flg + ((NIT - 1) % 3) * (NWG * 32) + (lane & 31) * 32;
            long gd = 0;
            for (;;) {
                float v = __hip_atomic_load(fb, __ATOMIC_RELAXED,
                                            __HIP_MEMORY_SCOPE_AGENT);
                if (__all(v > 0.0f)) break;
                if (++gd > 200000) break;
                __builtin_amdgcn_s_sleep(1);
            }
        }
        __syncthreads();
        const float* rb = cvec + ((NIT - 1) % 3) * (NWG * 1024) + tid;
        float c = 0.0f;
#pragma unroll
        for (int s2 = 0; s2 < NWG; ++s2)
            c += __hip_atomic_load(rb + s2 * 1024, __ATOMIC_RELAXED,
                                   __HIP_MEMORY_SCOPE_AGENT);
        sLp[uo * 66 + lo] = 1.0f / c;   // b for col tid
    }
    __syncthreads();

    // P(k,A=lane) and R(k,B=lane) for this thread's 2 rows (A-block == lane)
    float* Ps = buf;          // [32][64]
    float* Rs = buf + 2048;   // [32][64]
    float bl[16];
#pragma unroll
    for (int u = 0; u < 16; ++u) bl[u] = sLp[u * 66 + lane];
    {
        float p0 = 0.0f, r0 = 0.0f, p1 = 0.0f, r1 = 0.0f;
#pragma unroll
        for (int u = 0; u < 16; ++u) {
            p0 += C[0][u]; r0 += E[0][u] * bl[u];
            p1 += C[1][u]; r1 += E[1][u] * bl[u];
        }
        Ps[(rs * 2 + 0) * 64 + lane] = -p0;            // C = -Cl
        Rs[(rs * 2 + 0) * 64 + lane] = a0 * r0;
        Ps[(rs * 2 + 1) * 64 + lane] = -p1;
        Rs[(rs * 2 + 1) * 64 + lane] = a1 * r1;
    }
    __syncthreads();

    // G partial (this WG's 32 k-rows) -> atomicAdd into zeroed d_out
    float Rk[32];
#pragma unroll
    for (int k = 0; k < 32; ++k) Rk[k] = Rs[k * 64 + lane];  // B = lane
    const float sc = 1.0f / (256.0f * 1024.0f);
    float tsum = 0.0f;
#pragma unroll
    for (int q = 0; q < 4; ++q) {
        int o = tid + 1024 * q;
        int A = o >> 6;  // = rs + 16*q
        float acc = 0.0f;
#pragma unroll
        for (int k = 0; k < 32; ++k) acc += Ps[k * 64 + A] * Rk[k];
        float val = acc * sc;
        atomicAdd(out + o, val);
        if (A == lane) tsum += val;
    }
#pragma unroll
    for (int m = 1; m < 64; m <<= 1) tsum += __shfl_xor(tsum, m, 64);
    if (lane == 0) twv[rs] = tsum;
    __syncthreads();
    if (tid == 0) {
        float ts = 0.0f;
#pragma unroll
        for (int w = 0; w < 16; ++w) ts += twv[w];
        atomicAdd(out + 4096, ts);
    }
}

// ---------------------------------------------------------------------------
extern "C" void kernel_launch(void* const* d_in, const int* in_sizes, int n_in,
                              void* d_out, int out_size, void* d_ws, size_t ws_size,
                              hipStream_t stream) {
    const float* X = (const float*)d_in[0];  // t_prob [1024,512]
    const float* Y = (const float*)d_in[1];  // v_prob [1024,512]
    float* out = (float*)d_out;              // [64*64 + 1]
    float* ws  = (float*)d_ws;

    // zero ONLY the flag region (sign-parity tags; 0 matches neither) + d_out
    (void)hipMemsetAsync((char*)d_ws + (size_t)FLG_OFF * 4, 0,
                         (size_t)(3 * NWG * 32) * 4, stream);
    (void)hipMemsetAsync(d_out, 0, (size_t)out_size * 4, stream);

    k_gemm<<<dim3(16, 16), 256, 0, stream>>>(X, Y, ws);
    k_ipot<<<NWG, TPB, 0, stream>>>(ws, out);
}